// Round 8
// baseline (148.829 us; speedup 1.0000x reference)
//
#include <hip/hip_runtime.h>
#include <type_traits>

typedef __attribute__((ext_vector_type(8))) short short8;
typedef __attribute__((ext_vector_type(4))) short short4v;
typedef __attribute__((ext_vector_type(2))) short short2v;
typedef __attribute__((ext_vector_type(4))) float f32x4;
typedef unsigned short u16;
typedef unsigned int u32;

#define N_EDGES 448

// ws layout (u16 units); all-bf16 packs
#define WS_ADJA 0                    // 4096: A_norm, MFMA A-operand pack
#define WS_ADJB 4096                 // 4096: A_norm^T (legacy, unused by fused)
#define WS_W1   8192                 // 256x512, wave-grouped [w8][kk][s4]
#define WS_W2   139264               // 512x512, wave-grouped [w8][kk][s4]
#define WS_W3   401408               // 512x256, wave-grouped [w8][kk][s2]
#define WS_DUM  532480               // dummy 256 (KEYED) | b1 512 | b2 512 | b3 256
#define WS_B1   (WS_DUM + 256)
#define WS_B2   (WS_DUM + 768)
#define WS_B3   (WS_DUM + 1280)
#define WS_QE   534528               // 1024x256 qembs as KEYED bf16, row-major
#define WS_FLAG 796672               // u32: 1 = f32 inputs, 0 = bf16

__device__ __forceinline__ float bf2f(u16 v) {
    u32 u = ((u32)v) << 16;
    return __builtin_bit_cast(float, u);
}
__device__ __forceinline__ u16 f2bf(float f) {          // RNE (prep)
    u32 u = __builtin_bit_cast(u32, f);
    u32 r = u + 0x7FFFu + ((u >> 16) & 1u);
    return (u16)(r >> 16);
}
__device__ __forceinline__ u16 f2bf_fast(float f) {     // round-half-up (hot)
    u32 u = __builtin_bit_cast(u32, f);
    return (u16)((u + 0x8000u) >> 16);
}
__device__ __forceinline__ float ldf(const void* p, int idx, u32 isf32) {
    return isf32 ? ((const float*)p)[idx] : bf2f(((const u16*)p)[idx]);
}
// monotone bf16 <-> i16 key (involution): negatives get magnitude bits flipped,
// so signed-i16 compare == float compare. pk_max(i16) then equals fmax exactly.
__device__ __forceinline__ u16 keyb(u16 b) {
    return (u16)(b ^ ((u16)(((u16)((short)b >> 15)) >> 1)));
}
__device__ __forceinline__ u32 pkmax(u32 a, u32 b) {    // 2-lane packed i16 max
    short2v x = __builtin_bit_cast(short2v, a);
    short2v y = __builtin_bit_cast(short2v, b);
    short2v r = __builtin_elementwise_max(x, y);
    return __builtin_bit_cast(u32, r);
}

// ---------------------------------------------------------------------------
// prep: 512 blocks x 512 threads (proven, unchanged from R6).
//   all blocks: 2 weight chunks (t<128) + qembs->KEYED bf16 copy (t>=256)
//   block 0: adjacency + flag;  block 1: biases (plain) / dummy (KEYED)
// W packs wave-grouped: chunk = ((nt>>l2)*K32 + kk)<<l2 | (nt&(nsw-1)) so the
// fused K-loop uses ONE address stream + imm offsets (R6 spill fix, proven).
// ---------------------------------------------------------------------------
__global__ __launch_bounds__(512) void prep(
    const int* __restrict__ eidx, const void* __restrict__ ew,
    const void* __restrict__ qembs, const void* __restrict__ dummy,
    const void* __restrict__ W1, const void* __restrict__ b1,
    const void* __restrict__ W2, const void* __restrict__ b2,
    const void* __restrict__ W3, const void* __restrict__ b3,
    u16* __restrict__ ws) {
    const int t = threadIdx.x, bb = blockIdx.x;
    __shared__ u32 s_isf;
    if (t < 64) {
        const u16* qs = (const u16*)qembs;
        int c = 0;
#pragma unroll
        for (int j = 0; j < 4; j++) {
            u16 v = qs[(t * 4 + j) * 2];
            u32 e = (v >> 7) & 0xFF;
            c += (e >= 100 && e <= 134) ? 1 : 0;
        }
#pragma unroll
        for (int off = 32; off > 0; off >>= 1) c += __shfl_down(c, off, 64);
        if (t == 0) s_isf = (c < 128) ? 1u : 0u;
    }
    __syncthreads();
    const u32 isf32 = s_isf;

    if (t < 128) {
        const int bw = bb * 2 + (t >> 6);
        const int tl = t & 63;
        const void* src;
        int N, K32, dst, nt, kk, l2;
        if (bw < 256)      { src = W1; N = 512; K32 = 8;  dst = WS_W1; nt = bw / 8;          kk = bw % 8;         l2 = 2; }
        else if (bw < 768) { src = W2; N = 512; K32 = 16; dst = WS_W2; nt = (bw - 256) / 16; kk = (bw - 256) % 16; l2 = 2; }
        else               { src = W3; N = 256; K32 = 16; dst = WS_W3; nt = (bw - 768) / 16; kk = (bw - 768) % 16; l2 = 1; }
        const int col = nt * 16 + (tl & 15);
        const int krow = kk * 32 + (tl >> 4) * 8;
        u16 v[8];
#pragma unroll
        for (int j = 0; j < 8; j++) v[j] = f2bf(ldf(src, (krow + j) * N + col, isf32));
        const int chunk = ((((nt >> l2) * K32 + kk) << l2) | (nt & ((1 << l2) - 1)));
        u16* o = ws + dst + chunk * 512 + tl * 8;
#pragma unroll
        for (int j = 0; j < 8; j++) o[j] = v[j];
    }
    if (t >= 256) {
        const int base = bb * 512 + (t - 256) * 2;
        ws[WS_QE + base]     = keyb(f2bf(ldf(qembs, base, isf32)));
        ws[WS_QE + base + 1] = keyb(f2bf(ldf(qembs, base + 1, isf32)));
    }
    if (bb == 1) {
#pragma unroll
        for (int j = 0; j < 4; j++) {
            int i = t + j * 512;
            if (i < 1792) {
                u16 o;
                if (i < 256)       o = keyb(f2bf(ldf(dummy, i, isf32)));
                else if (i < 768)  o = f2bf(ldf(b1, i - 256, isf32));
                else if (i < 1280) o = f2bf(ldf(b2, i - 768, isf32));
                else               o = f2bf(ldf(b3, i - 1280, isf32));
                ws[WS_DUM + i] = o;
            }
        }
    }
    if (bb == 0) {
        __shared__ float A[4096];
        __shared__ float deg[64];
        __shared__ float dinv[64];
        __shared__ int er[N_EDGES];
        __shared__ int ec[N_EDGES];
        __shared__ float ewf[N_EDGES];
        if (t < N_EDGES) {
            er[t] = eidx[t];
            ec[t] = eidx[N_EDGES + t];
            ewf[t] = ldf(ew, t, isf32);
        }
        if (t < 64) deg[t] = 1.0f;
        for (int i = t; i < 4096; i += 512) A[i] = 0.f;
        __syncthreads();
        if (t < N_EDGES) atomicAdd(&deg[ec[t]], ewf[t]);
        __syncthreads();
        if (t < 64) dinv[t] = 1.0f / sqrtf(deg[t]);
        __syncthreads();
        if (t < N_EDGES) atomicAdd(&A[ec[t] * 64 + er[t]], dinv[er[t]] * ewf[t] * dinv[ec[t]]);
        __syncthreads();
        if (t < 64) A[t * 64 + t] += dinv[t] * dinv[t];
        __syncthreads();
        for (int i = t; i < 4096; i += 512) {
            int chunk = i >> 9, m = (i >> 3) & 63, j = i & 7;
            ws[WS_ADJA + i] = f2bf(A[m * 64 + chunk * 8 + j]);
        }
        for (int i = t; i < 4096; i += 512) {
            int chunk = i >> 9, l = (i >> 3) & 63, j = i & 7;
            int ntc = chunk >> 1, kk = chunk & 1;
            int k = kk * 32 + (l >> 4) * 8 + j;
            int c2 = ntc * 16 + (l & 15);
            ws[WS_ADJB + i] = f2bf(A[c2 * 64 + k]);
        }
        if (t == 0) *(u32*)(ws + WS_FLAG) = isf32;
    }
}

// ---------------------------------------------------------------------------
// fused R8: R7's pre-multiply structure + OPERAND-SWAPPED preMM.
// R7 regression root-cause: preMM epilogue wrote g to A-pack as stride-8 u16
// scatters (thread held 4 consecutive ROWS for fixed col) -> +3.3M bank
// conflicts ~= +5 us. Fix: compute mfma(hb, aA) instead of mfma(aA, hb).
// The h B-pack IS h^T in A-operand form and the ADJA pack IS A^T in
// B-operand form (identical lane mappings), so the same data produces g^T
// in C-layout: thread holds fixed CORE + 4 consecutive DIMS -> the A-pack
// write is an aligned short4v (16 byte-slots x 4 lanes = full BW, zero
// conflict), same as mainMM's proven B-pack epilogue. Same MFMA count,
// same registers, same in-place window. Also: XOR-swizzle the f32 staging
// buffer (n ^= ((m>>2)&7)<<2, write and read) to kill the 4-way quad
// conflict in the FOUT epilogue.
// Spill gate: FETCH > 15 MB => revert.
// ---------------------------------------------------------------------------
__global__ __launch_bounds__(1024, 4) void fused(
    const int* __restrict__ allocs, const u16* __restrict__ ws,
    void* __restrict__ out) {

    __shared__ __align__(16) u16 BUF[2][64 * 512];   // 2 x 64 KB

    const int t = threadIdx.x, bb = blockIdx.x;
    const int wave = t >> 6, lane = t & 63, quad = lane >> 4, nl = lane & 15;
    const int he = wave >> 3;          // element half: waves 0-7 -> 0, 8-15 -> 1
    const int w8 = wave & 7;           // wave index within half
    const u32 isf32 = *(const u32*)(ws + WS_FLAG);
    const int e0 = bb * 2;

    // ---- pooling: counting sort for both elements (all threads), then each
    // wave-half gathers 8 cores of ITS element -> X B-PACK in BUF[he] 0..31 --
    {
        int* LISTA = (int*)(BUF[0] + 16384);
        int* CNTA  = LISTA + 1024;
        int* SSTA  = CNTA + 64;
        int* WOFA  = SSTA + 64;
        int* LISTB = (int*)(BUF[1] + 16384);
        int* CNTB  = LISTB + 1024;
        int* SSTB  = CNTB + 64;
        int* WOFB  = SSTB + 64;
        if (t < 64) { CNTA[t] = 0; CNTB[t] = 0; }
        __syncthreads();
        const int ca = allocs[e0 * 1024 + t];
        const int cb = allocs[(e0 + 1) * 1024 + t];
        atomicAdd(&CNTA[ca], 1);
        atomicAdd(&CNTB[cb], 1);
        __syncthreads();
        if (t < 128) {
            const int l = t & 63;
            int* C  = (t < 64) ? CNTA : CNTB;
            int* S  = (t < 64) ? SSTA : SSTB;
            int* Wo = (t < 64) ? WOFA : WOFB;
            int v = C[l], s = v;
#pragma unroll
            for (int off = 1; off < 64; off <<= 1) {
                int u = __shfl_up(s, off, 64);
                if (l >= off) s += u;
            }
            S[l] = s - v;
            Wo[l] = s - v;
        }
        __syncthreads();
        {
            int pa = atomicAdd(&WOFA[ca], 1); LISTA[pa] = t;
            int pb = atomicAdd(&WOFB[cb], 1); LISTB[pb] = t;
        }
        __syncthreads();
        // wave-half owns cores w8*8..+7 of element he; lane owns dims lane*4..+3
        const u16* wsq = ws + WS_QE;
        const uint2 dk = *(const uint2*)(ws + WS_DUM + lane * 4);  // keyed dummy
        const int* LIST = he ? LISTB : LISTA;
        const int* CNT  = he ? CNTB  : CNTA;
        const int* SST  = he ? SSTB  : SSTA;
        u16* XB = BUF[he];
        for (int i = 0; i < 8; i++) {
            const int c = w8 * 8 + i;
            const int L = CNT[c], S = SST[c];
            u32 m0 = dk.x, m1 = dk.y;
            int j = 0;
            for (; j + 4 <= L; j += 4) {
                const int q0 = LIST[S + j],     q1 = LIST[S + j + 1];
                const int q2 = LIST[S + j + 2], q3 = LIST[S + j + 3];
                uint2 ra = *(const uint2*)(wsq + q0 * 256 + lane * 4);
                uint2 rb = *(const uint2*)(wsq + q1 * 256 + lane * 4);
                uint2 rc = *(const uint2*)(wsq + q2 * 256 + lane * 4);
                uint2 rd = *(const uint2*)(wsq + q3 * 256 + lane * 4);
                m0 = pkmax(pkmax(m0, ra.x), pkmax(rb.x, rc.x));
                m1 = pkmax(pkmax(m1, ra.y), pkmax(rb.y, rc.y));
                m0 = pkmax(m0, rd.x);
                m1 = pkmax(m1, rd.y);
            }
            for (; j < L; j++) {
                const int q = LIST[S + j];
                uint2 r = *(const uint2*)(wsq + q * 256 + lane * 4);
                m0 = pkmax(m0, r.x);
                m1 = pkmax(m1, r.y);
            }
            u16 vv[4];                     // un-key -> exact bf16 max
            vv[0] = keyb((u16)(m0 & 0xffffu));
            vv[1] = keyb((u16)(m0 >> 16));
            vv[2] = keyb((u16)(m1 & 0xffffu));
            vv[3] = keyb((u16)(m1 >> 16));
            // B-pack write: (core c, dim n=lane*4+ii) -> chunk (n>>4)*2+(c>>5),
            // slot ((c>>3)&3)*16 + (n&15), byte c&7. 4 u16 scatter, stride 8.
            u16* dst = XB + ((lane >> 2) * 2 + (c >> 5)) * 512
                          + (((c >> 3) & 3) * 16 + (lane & 3) * 4) * 8 + (c & 7);
#pragma unroll
            for (int ii = 0; ii < 4; ii++) dst[ii * 8] = vv[ii];
        }
    }
    __syncthreads();

    // preMM (operand-swapped): acc = mfma(hb, aA) computes g^T in C-layout
    // (col = core, rows = dims). aA from L2-hot WS_ADJA doubles as A^T in
    // B-operand form. Write g to A-pack as contiguous short4v:
    // chunk 4g + ntL*2 + (quad>>1), pos (rt*16+nl)*8 + (quad&1)*4 + rr.
    auto preMM = [&](int NG) {
        short8 aA[2][4];
#pragma unroll
        for (int kkc = 0; kkc < 2; kkc++)
#pragma unroll
            for (int rt = 0; rt < 4; rt++)
                aA[kkc][rt] = *(const short8*)(ws + WS_ADJA + (kkc * 4 + quad) * 512 + (rt * 16 + nl) * 8);
        for (int gi = 0; gi < NG; gi++) {
            const int g = w8 + gi * 8;
            u16* base = BUF[he] + (g * 4) * 512;
            short8 hb[2][2];   // [ntL][kkc]
#pragma unroll
            for (int ntL = 0; ntL < 2; ntL++)
#pragma unroll
                for (int kkc = 0; kkc < 2; kkc++)
                    hb[ntL][kkc] = *(const short8*)(base + (ntL * 2 + kkc) * 512 + lane * 8);
            f32x4 acc[4][2];   // [rt = core-tile][ntL = dim-tile]
#pragma unroll
            for (int rt = 0; rt < 4; rt++)
#pragma unroll
                for (int ntL = 0; ntL < 2; ntL++) acc[rt][ntL] = f32x4{0.f, 0.f, 0.f, 0.f};
#pragma unroll
            for (int kkc = 0; kkc < 2; kkc++)
#pragma unroll
                for (int ntL = 0; ntL < 2; ntL++)
#pragma unroll
                    for (int rt = 0; rt < 4; rt++)
                        acc[rt][ntL] = __builtin_amdgcn_mfma_f32_16x16x32_bf16(hb[ntL][kkc], aA[kkc][rt], acc[rt][ntL], 0, 0, 0);
            // g[m=core][k=dim]: thread holds m = rt*16+nl, k = g*32 + ntL*16
            // + quad*4 + rr -> short4v at chunk ntL*2+(quad>>1),
            // pos (rt*16+nl)*8 + (quad&1)*4. Contiguous, conflict-free.
#pragma unroll
            for (int ntL = 0; ntL < 2; ntL++)
#pragma unroll
                for (int rt = 0; rt < 4; rt++) {
                    short4v p;
#pragma unroll
                    for (int rr = 0; rr < 4; rr++) p[rr] = (short)f2bf_fast(acc[rt][ntL][rr]);
                    *(short4v*)(base + (ntL * 2 + (quad >> 1)) * 512
                                + (rt * 16 + nl) * 8 + (quad & 1) * 4) = p;
                }
        }
    };

    // mainMM: h' = relu(g@W + b). K-loop = R6's proven shape (one W addr
    // stream, s-paired bch, acc[NS][4]). Epilogue: C-layout -> B-pack direct
    // (FOUT=false) or relu+bias -> swizzled f32 staging (FOUT=true, L3).
    auto mainMM = [&](auto K32c, auto NSc, auto FOUTc, const u16* __restrict__ W,
                      const u16* __restrict__ bias) {
        constexpr int K32 = decltype(K32c)::value;
        constexpr int NS  = decltype(NSc)::value;
        constexpr bool FOUT = decltype(FOUTc)::value;
        const int s0 = w8 * NS;
        const u16* wp = W + (w8 * K32 * NS) * 512 + lane * 8;   // one addr stream
        f32x4 acc[NS][4];
#pragma unroll
        for (int s = 0; s < NS; s++)
#pragma unroll
            for (int rt = 0; rt < 4; rt++) acc[s][rt] = f32x4{0.f, 0.f, 0.f, 0.f};
#pragma unroll 2
        for (int kk = 0; kk < K32; kk++) {
            short8 a[4];
#pragma unroll
            for (int rt = 0; rt < 4; rt++)
                a[rt] = *(const short8*)(BUF[he] + (kk * 4 + quad) * 512 + (rt * 16 + nl) * 8);
            const u16* wk = wp + kk * NS * 512;
#pragma unroll
            for (int sp = 0; sp < NS; sp += 2) {
                short8 b0 = *(const short8*)(wk + sp * 512);
                short8 b1 = *(const short8*)(wk + (sp + 1) * 512);
#pragma unroll
                for (int rt = 0; rt < 4; rt++)
                    acc[sp][rt] = __builtin_amdgcn_mfma_f32_16x16x32_bf16(a[rt], b0, acc[sp][rt], 0, 0, 0);
#pragma unroll
                for (int rt = 0; rt < 4; rt++)
                    acc[sp + 1][rt] = __builtin_amdgcn_mfma_f32_16x16x32_bf16(a[rt], b1, acc[sp + 1][rt], 0, 0, 0);
            }
        }
        __syncthreads();   // all g reads complete -> in-place writes legal
        if constexpr (!FOUT) {
#pragma unroll
            for (int s = 0; s < NS; s++) {
                const int nt = s0 + s;
                const float bvv = bf2f(bias[nt * 16 + nl]);   // bias on cols: one per thread
#pragma unroll
                for (int rt = 0; rt < 4; rt++) {
                    short4v p;
#pragma unroll
                    for (int rr = 0; rr < 4; rr++)
                        p[rr] = (short)f2bf_fast(fmaxf(acc[s][rt][rr] + bvv, 0.f));
                    // B-pack: (m = rt*16+quad*4+rr, n = nt*16+nl)
                    *(short4v*)(BUF[he] + (nt * 2 + (rt >> 1)) * 512
                                + (((rt & 1) * 2 + (quad >> 1)) * 16 + nl) * 8
                                + (quad & 1) * 4) = p;
                }
            }
        } else {
            float* Hf = (float*)BUF[he];
#pragma unroll
            for (int s = 0; s < NS; s++) {
                const int n = (s0 + s) * 16 + nl;
                const float bvv = bf2f(bias[n]);
#pragma unroll
                for (int rt = 0; rt < 4; rt++)
#pragma unroll
                    for (int rr = 0; rr < 4; rr++) {
                        const int m = rt * 16 + quad * 4 + rr;
                        Hf[m * 256 + (n ^ (((m >> 2) & 7) << 2))] = fmaxf(acc[s][rt][rr] + bvv, 0.f);
                    }
            }
        }
        __syncthreads();
    };

    // L1: h0=X(256) -> g1 -> h1(512); L2: 512->512; L3: 512 -> f32 out stage
    preMM(1);
    __syncthreads();
    mainMM(std::integral_constant<int, 8>{},  std::integral_constant<int, 4>{},
           std::integral_constant<bool, false>{}, ws + WS_W1, ws + WS_B1);
    preMM(2);
    __syncthreads();
    mainMM(std::integral_constant<int, 16>{}, std::integral_constant<int, 4>{},
           std::integral_constant<bool, false>{}, ws + WS_W2, ws + WS_B2);
    preMM(2);
    __syncthreads();
    mainMM(std::integral_constant<int, 16>{}, std::integral_constant<int, 2>{},
           std::integral_constant<bool, true>{},  ws + WS_W3, ws + WS_B3);

    // store: coalesced, both elements (f32 staged SWIZZLED in BUF[e] by L3).
    // Each thread's float4 is 4 consecutive n within one row m2; the XOR is
    // on n bits 2-4 so a 4-aligned block stays contiguous.
    {
#pragma unroll
        for (int e = 0; e < 2; e++) {
            const float* Hf = (const float*)BUF[e];
            if (isf32) {
                float4* outv = (float4*)((float*)out + (size_t)(e0 + e) * 16384);
#pragma unroll
                for (int p4 = 0; p4 < 4; p4++) {
                    const int idx = (p4 * 1024 + t) * 4;
                    const int m2 = idx >> 8, n0 = idx & 255;
                    outv[p4 * 1024 + t] =
                        *(const float4*)(Hf + m2 * 256 + (n0 ^ (((m2 >> 2) & 7) << 2)));
                }
            } else {
                u16* outu = (u16*)out + (size_t)(e0 + e) * 16384;
#pragma unroll
                for (int p4 = 0; p4 < 4; p4++) {
                    const int idx = (p4 * 1024 + t) * 4;
                    const int m2 = idx >> 8, n0 = idx & 255;
                    float4 v = *(const float4*)(Hf + m2 * 256 + (n0 ^ (((m2 >> 2) & 7) << 2)));
                    short4v pk;
                    pk[0] = (short)f2bf_fast(v.x); pk[1] = (short)f2bf_fast(v.y);
                    pk[2] = (short)f2bf_fast(v.z); pk[3] = (short)f2bf_fast(v.w);
                    *(short4v*)(outu + idx) = pk;
                }
            }
        }
    }
}

// ---------------------------------------------------------------------------
extern "C" void kernel_launch(void* const* d_in, const int* in_sizes, int n_in,
                              void* d_out, int out_size, void* d_ws, size_t ws_size,
                              hipStream_t stream) {
    const int* allocs = (const int*)d_in[0];
    const void* qembs = d_in[1];
    const void* dummy = d_in[2];
    const int* eidx   = (const int*)d_in[3];
    const void* ew    = d_in[4];
    const void* W1 = d_in[5];
    const void* b1 = d_in[6];
    const void* W2 = d_in[7];
    const void* b2 = d_in[8];
    const void* W3 = d_in[9];
    const void* b3 = d_in[10];
    u16* ws = (u16*)d_ws;

    prep<<<512, 512, 0, stream>>>(eidx, ew, qembs, dummy, W1, b1, W2, b2, W3, b3, ws);
    fused<<<256, 1024, 0, stream>>>(allocs, ws, d_out);
}

// Round 9
// 139.672 us; speedup vs baseline: 1.0656x; 1.0656x over previous
//
#include <hip/hip_runtime.h>
#include <type_traits>

typedef __attribute__((ext_vector_type(8))) short short8;
typedef __attribute__((ext_vector_type(4))) short short4v;
typedef __attribute__((ext_vector_type(2))) short short2v;
typedef __attribute__((ext_vector_type(4))) float f32x4;
typedef unsigned short u16;
typedef unsigned int u32;

#define N_EDGES 448

// ws layout (u16 units); all-bf16 packs
#define WS_ADJA 0                    // 4096: A_norm, MFMA A-operand pack
#define WS_ADJB 4096                 // 4096: A_norm^T, MFMA B-operand pack
#define WS_W1   8192                 // 256x512, wave-grouped [w][kk][s4]
#define WS_W2   139264               // 512x512, wave-grouped [w][kk][s4]
#define WS_W3   401408               // 512x256, wave-grouped [w][kk][s2]
#define WS_DUM  532480               // dummy 256 (KEYED) | b1 512 | b2 512 | b3 256
#define WS_B1   (WS_DUM + 256)
#define WS_B2   (WS_DUM + 768)
#define WS_B3   (WS_DUM + 1280)
#define WS_QE   534528               // 1024x256 qembs as KEYED bf16, row-major
#define WS_FLAG 796672               // u32: 1 = f32 inputs, 0 = bf16

__device__ __forceinline__ float bf2f(u16 v) {
    u32 u = ((u32)v) << 16;
    return __builtin_bit_cast(float, u);
}
__device__ __forceinline__ u16 f2bf(float f) {          // RNE (prep)
    u32 u = __builtin_bit_cast(u32, f);
    u32 r = u + 0x7FFFu + ((u >> 16) & 1u);
    return (u16)(r >> 16);
}
__device__ __forceinline__ u16 f2bf_fast(float f) {     // round-half-up (hot)
    u32 u = __builtin_bit_cast(u32, f);
    return (u16)((u + 0x8000u) >> 16);
}
__device__ __forceinline__ float ldf(const void* p, int idx, u32 isf32) {
    return isf32 ? ((const float*)p)[idx] : bf2f(((const u16*)p)[idx]);
}
// monotone bf16 <-> i16 key (involution): negatives get magnitude bits flipped,
// so signed-i16 compare == float compare. pk_max(i16) then equals fmax exactly.
__device__ __forceinline__ u16 keyb(u16 b) {
    return (u16)(b ^ ((u16)(((u16)((short)b >> 15)) >> 1)));
}
__device__ __forceinline__ u32 pkmax(u32 a, u32 b) {    // 2-lane packed i16 max
    short2v x = __builtin_bit_cast(short2v, a);
    short2v y = __builtin_bit_cast(short2v, b);
    short2v r = __builtin_elementwise_max(x, y);
    return __builtin_bit_cast(u32, r);
}

// ---------------------------------------------------------------------------
// prep: 512 blocks x 512 threads (proven, unchanged from R6).
//   all blocks: 2 weight chunks (t<128) + qembs->KEYED bf16 copy (t>=256)
//   block 0: adjacency + flag;  block 1: biases (plain) / dummy (KEYED)
// W packs wave-grouped: chunk = ((nt>>l2)*K32 + kk)<<l2 | (nt&(nsw-1)) so the
// fused K-loop uses ONE address stream + imm offsets (R6 spill fix, proven).
// ---------------------------------------------------------------------------
__global__ __launch_bounds__(512) void prep(
    const int* __restrict__ eidx, const void* __restrict__ ew,
    const void* __restrict__ qembs, const void* __restrict__ dummy,
    const void* __restrict__ W1, const void* __restrict__ b1,
    const void* __restrict__ W2, const void* __restrict__ b2,
    const void* __restrict__ W3, const void* __restrict__ b3,
    u16* __restrict__ ws) {
    const int t = threadIdx.x, bb = blockIdx.x;
    __shared__ u32 s_isf;
    if (t < 64) {
        const u16* qs = (const u16*)qembs;
        int c = 0;
#pragma unroll
        for (int j = 0; j < 4; j++) {
            u16 v = qs[(t * 4 + j) * 2];
            u32 e = (v >> 7) & 0xFF;
            c += (e >= 100 && e <= 134) ? 1 : 0;
        }
#pragma unroll
        for (int off = 32; off > 0; off >>= 1) c += __shfl_down(c, off, 64);
        if (t == 0) s_isf = (c < 128) ? 1u : 0u;
    }
    __syncthreads();
    const u32 isf32 = s_isf;

    if (t < 128) {
        const int bw = bb * 2 + (t >> 6);
        const int tl = t & 63;
        const void* src;
        int N, K32, dst, nt, kk, l2;
        if (bw < 256)      { src = W1; N = 512; K32 = 8;  dst = WS_W1; nt = bw / 8;          kk = bw % 8;         l2 = 2; }
        else if (bw < 768) { src = W2; N = 512; K32 = 16; dst = WS_W2; nt = (bw - 256) / 16; kk = (bw - 256) % 16; l2 = 2; }
        else               { src = W3; N = 256; K32 = 16; dst = WS_W3; nt = (bw - 768) / 16; kk = (bw - 768) % 16; l2 = 1; }
        const int col = nt * 16 + (tl & 15);
        const int krow = kk * 32 + (tl >> 4) * 8;
        u16 v[8];
#pragma unroll
        for (int j = 0; j < 8; j++) v[j] = f2bf(ldf(src, (krow + j) * N + col, isf32));
        const int chunk = ((((nt >> l2) * K32 + kk) << l2) | (nt & ((1 << l2) - 1)));
        u16* o = ws + dst + chunk * 512 + tl * 8;
#pragma unroll
        for (int j = 0; j < 8; j++) o[j] = v[j];
    }
    if (t >= 256) {
        const int base = bb * 512 + (t - 256) * 2;
        ws[WS_QE + base]     = keyb(f2bf(ldf(qembs, base, isf32)));
        ws[WS_QE + base + 1] = keyb(f2bf(ldf(qembs, base + 1, isf32)));
    }
    if (bb == 1) {
#pragma unroll
        for (int j = 0; j < 4; j++) {
            int i = t + j * 512;
            if (i < 1792) {
                u16 o;
                if (i < 256)       o = keyb(f2bf(ldf(dummy, i, isf32)));
                else if (i < 768)  o = f2bf(ldf(b1, i - 256, isf32));
                else if (i < 1280) o = f2bf(ldf(b2, i - 768, isf32));
                else               o = f2bf(ldf(b3, i - 1280, isf32));
                ws[WS_DUM + i] = o;
            }
        }
    }
    if (bb == 0) {
        __shared__ float A[4096];
        __shared__ float deg[64];
        __shared__ float dinv[64];
        __shared__ int er[N_EDGES];
        __shared__ int ec[N_EDGES];
        __shared__ float ewf[N_EDGES];
        if (t < N_EDGES) {
            er[t] = eidx[t];
            ec[t] = eidx[N_EDGES + t];
            ewf[t] = ldf(ew, t, isf32);
        }
        if (t < 64) deg[t] = 1.0f;
        for (int i = t; i < 4096; i += 512) A[i] = 0.f;
        __syncthreads();
        if (t < N_EDGES) atomicAdd(&deg[ec[t]], ewf[t]);
        __syncthreads();
        if (t < 64) dinv[t] = 1.0f / sqrtf(deg[t]);
        __syncthreads();
        if (t < N_EDGES) atomicAdd(&A[ec[t] * 64 + er[t]], dinv[er[t]] * ewf[t] * dinv[ec[t]]);
        __syncthreads();
        if (t < 64) A[t * 64 + t] += dinv[t] * dinv[t];
        __syncthreads();
        for (int i = t; i < 4096; i += 512) {
            int chunk = i >> 9, m = (i >> 3) & 63, j = i & 7;
            ws[WS_ADJA + i] = f2bf(A[m * 64 + chunk * 8 + j]);
        }
        for (int i = t; i < 4096; i += 512) {
            int chunk = i >> 9, l = (i >> 3) & 63, j = i & 7;
            int ntc = chunk >> 1, kk = chunk & 1;
            int k = kk * 32 + (l >> 4) * 8 + j;
            int c2 = ntc * 16 + (l & 15);
            ws[WS_ADJB + i] = f2bf(A[c2 * 64 + k]);
        }
        if (t == 0) *(u32*)(ws + WS_FLAG) = isf32;
    }
}

// ---------------------------------------------------------------------------
// fused R9: R6's per-element program repackaged as its own BLOCK.
// 512 blocks x 512 threads (8 waves), ONE element per block.
// Rationale: regs = 64 arch + 64 acc = 128/wave -> hard cap 16 waves/CU.
// A 1024-thread block IS 16 waves, so a second block could never co-reside
// (blocks are atomic) -> every barrier was a full-CU drain with nothing to
// hide it. 8-wave blocks: LDS 72KB x2 = 144 <= 160KB, 2 blocks/CU, same 16
// waves but two INDEPENDENT barrier domains -> block B's MFMAs cover block
// A's barrier/vmcnt drains and serial pooling gathers.
// Per-wave code is byte-identical to R6's wave-half (he fixed, w8 -> wave):
// 4 N-stripes/wave, one W addr stream + imm offsets, acc[4][4] (proven
// no-spill). Spill gate stays: FETCH > 20 MB => revert.
// ---------------------------------------------------------------------------
__global__ __launch_bounds__(512, 4) void fused(
    const int* __restrict__ allocs, const u16* __restrict__ ws,
    void* __restrict__ out) {

    __shared__ __align__(16) u16 BUF[64 * 512];      // 64 KB
    __shared__ __align__(16) u16 ADJB_S[4096];       // 8 KB: A_norm^T B-pack

    const int t = threadIdx.x, bb = blockIdx.x;
    const int wave = t >> 6, lane = t & 63, quad = lane >> 4, nl = lane & 15;
    const u32 isf32 = *(const u32*)(ws + WS_FLAG);

    *(uint4*)(ADJB_S + t * 8) = *(const uint4*)(ws + WS_ADJB + t * 8);

    // ---- pooling: counting sort (2 qubits/thread), then each wave gathers
    // 8 cores -> X A-pack in BUF chunks 0..31. Aux in chunks 32+ (dead). ----
    {
        int* LIST = (int*)(BUF + 16384);
        int* CNT  = LIST + 1024;
        int* SST  = CNT + 64;
        int* WOF  = SST + 64;
        if (t < 64) CNT[t] = 0;
        __syncthreads();
        const int c0 = allocs[bb * 1024 + t];
        const int c1 = allocs[bb * 1024 + 512 + t];
        atomicAdd(&CNT[c0], 1);
        atomicAdd(&CNT[c1], 1);
        __syncthreads();
        if (t < 64) {
            int v = CNT[t], s = v;
#pragma unroll
            for (int off = 1; off < 64; off <<= 1) {
                int u = __shfl_up(s, off, 64);
                if (t >= off) s += u;
            }
            SST[t] = s - v;
            WOF[t] = s - v;
        }
        __syncthreads();
        {
            int p0 = atomicAdd(&WOF[c0], 1); LIST[p0] = t;
            int p1 = atomicAdd(&WOF[c1], 1); LIST[p1] = 512 + t;
        }
        __syncthreads();
        // wave owns cores wave*8..+7; lane owns dims lane*4..+3
        const u16* wsq = ws + WS_QE;
        const uint2 dk = *(const uint2*)(ws + WS_DUM + lane * 4);  // keyed dummy
        for (int i = 0; i < 8; i++) {
            const int c = wave * 8 + i;
            const int L = CNT[c], S = SST[c];
            u32 m0 = dk.x, m1 = dk.y;
            int j = 0;
            for (; j + 4 <= L; j += 4) {
                const int q0 = LIST[S + j],     q1 = LIST[S + j + 1];
                const int q2 = LIST[S + j + 2], q3 = LIST[S + j + 3];
                uint2 ra = *(const uint2*)(wsq + q0 * 256 + lane * 4);
                uint2 rb = *(const uint2*)(wsq + q1 * 256 + lane * 4);
                uint2 rc = *(const uint2*)(wsq + q2 * 256 + lane * 4);
                uint2 rd = *(const uint2*)(wsq + q3 * 256 + lane * 4);
                m0 = pkmax(pkmax(m0, ra.x), pkmax(rb.x, rc.x));
                m1 = pkmax(pkmax(m1, ra.y), pkmax(rb.y, rc.y));
                m0 = pkmax(m0, rd.x);
                m1 = pkmax(m1, rd.y);
            }
            for (; j < L; j++) {
                const int q = LIST[S + j];
                uint2 r = *(const uint2*)(wsq + q * 256 + lane * 4);
                m0 = pkmax(m0, r.x);
                m1 = pkmax(m1, r.y);
            }
            short4v p;                     // un-key -> exact bf16 max
            p[0] = (short)keyb((u16)(m0 & 0xffffu));
            p[1] = (short)keyb((u16)(m0 >> 16));
            p[2] = (short)keyb((u16)(m1 & 0xffffu));
            p[3] = (short)keyb((u16)(m1 >> 16));
            *(short4v*)(BUF + (lane >> 1) * 512 + c * 8 + (lane & 1) * 4) = p;
        }
    }
    __syncthreads();

    // layerT (in-place over BUF): mm1 (4 stripes/wave, s-paired bch from the
    // wave-grouped pack, ONE addr stream) -> mid barrier -> per s: transpose
    // + agg(adjB from LDS) + relu/bias -> wave-owned chunks 8w..8w+7.
    // scr = chunks 8w+6..7, consumed before the s=3 epilogue overwrites them.
    auto layerT = [&](auto K32c, const u16* __restrict__ W, const u16* __restrict__ bias) {
        constexpr int K32 = decltype(K32c)::value;
        const int s0 = wave * 4;
        u16* scr = BUF + (wave * 8 + 6) * 512;
        const u16* wp = W + (wave * K32 * 4) * 512 + lane * 8;   // one addr stream
        f32x4 acc[4][4];
#pragma unroll
        for (int s = 0; s < 4; s++)
#pragma unroll
            for (int rt = 0; rt < 4; rt++) acc[s][rt] = f32x4{0.f, 0.f, 0.f, 0.f};
#pragma unroll 2
        for (int kk = 0; kk < K32; kk++) {
            short8 a[4];
#pragma unroll
            for (int rt = 0; rt < 4; rt++)
                a[rt] = *(const short8*)(BUF + (kk * 4 + quad) * 512 + (rt * 16 + nl) * 8);
            const u16* wk = wp + kk * 4 * 512;
            {
                short8 b0 = *(const short8*)(wk);
                short8 b1 = *(const short8*)(wk + 512);
#pragma unroll
                for (int rt = 0; rt < 4; rt++)
                    acc[0][rt] = __builtin_amdgcn_mfma_f32_16x16x32_bf16(a[rt], b0, acc[0][rt], 0, 0, 0);
#pragma unroll
                for (int rt = 0; rt < 4; rt++)
                    acc[1][rt] = __builtin_amdgcn_mfma_f32_16x16x32_bf16(a[rt], b1, acc[1][rt], 0, 0, 0);
            }
            {
                short8 b2 = *(const short8*)(wk + 1024);
                short8 b3 = *(const short8*)(wk + 1536);
#pragma unroll
                for (int rt = 0; rt < 4; rt++)
                    acc[2][rt] = __builtin_amdgcn_mfma_f32_16x16x32_bf16(a[rt], b2, acc[2][rt], 0, 0, 0);
#pragma unroll
                for (int rt = 0; rt < 4; rt++)
                    acc[3][rt] = __builtin_amdgcn_mfma_f32_16x16x32_bf16(a[rt], b3, acc[3][rt], 0, 0, 0);
            }
        }
        __syncthreads();   // all BUF reads complete -> in-place writes legal
#pragma unroll
        for (int s = 0; s < 4; s++) {
            const int nt = s0 + s;
            float bv[4];
#pragma unroll
            for (int rr = 0; rr < 4; rr++) bv[rr] = bf2f(bias[nt * 16 + quad * 4 + rr]);
            f32x4 agg[4];
#pragma unroll
            for (int ntc = 0; ntc < 4; ntc++) agg[ntc] = f32x4{0.f, 0.f, 0.f, 0.f};
#pragma unroll
            for (int h = 0; h < 2; h++) {
#pragma unroll
                for (int r2 = 0; r2 < 2; r2++) {
                    f32x4 v = acc[s][2 * h + r2];
                    short4v p;
#pragma unroll
                    for (int rr = 0; rr < 4; rr++) p[rr] = (short)f2bf_fast(v[rr]);
                    *(short4v*)(scr + nl * 40 + r2 * 16 + quad * 4) = p;
                }
                short8 hwf = *(const short8*)(scr + nl * 40 + quad * 8);
#pragma unroll
                for (int ntc = 0; ntc < 4; ntc++) {
                    short8 bfrag = *(const short8*)(ADJB_S + (ntc * 2 + h) * 512 + lane * 8);
                    agg[ntc] = __builtin_amdgcn_mfma_f32_16x16x32_bf16(hwf, bfrag, agg[ntc], 0, 0, 0);
                }
            }
#pragma unroll
            for (int ntc = 0; ntc < 4; ntc++) {
                short4v p;
#pragma unroll
                for (int rr = 0; rr < 4; rr++)
                    p[rr] = (short)f2bf_fast(fmaxf(agg[ntc][rr] + bv[rr], 0.f));
                *(short4v*)(BUF + (nt * 2 + (quad >> 1)) * 512 + (ntc * 16 + nl) * 8 + (quad & 1) * 4) = p;
            }
        }
        __syncthreads();
    };

    // layer3 (in-place): hw3 = h2 @ W3 (2 stripes/wave, paired bch) ->
    // mid barrier -> B-pack into chunks 0..31; scr in chunks 32+ (dead).
    auto layer3 = [&](const u16* __restrict__ W) {
        const u16* wp = W + (wave * 16 * 2) * 512 + lane * 8;
        f32x4 acc[2][4];
#pragma unroll
        for (int s = 0; s < 2; s++)
#pragma unroll
            for (int rt = 0; rt < 4; rt++) acc[s][rt] = f32x4{0.f, 0.f, 0.f, 0.f};
#pragma unroll 2
        for (int kk = 0; kk < 16; kk++) {
            short8 a[4];
#pragma unroll
            for (int rt = 0; rt < 4; rt++)
                a[rt] = *(const short8*)(BUF + (kk * 4 + quad) * 512 + (rt * 16 + nl) * 8);
            const u16* wk = wp + kk * 2 * 512;
            short8 b0 = *(const short8*)(wk);
            short8 b1 = *(const short8*)(wk + 512);
#pragma unroll
            for (int rt = 0; rt < 4; rt++)
                acc[0][rt] = __builtin_amdgcn_mfma_f32_16x16x32_bf16(a[rt], b0, acc[0][rt], 0, 0, 0);
#pragma unroll
            for (int rt = 0; rt < 4; rt++)
                acc[1][rt] = __builtin_amdgcn_mfma_f32_16x16x32_bf16(a[rt], b1, acc[1][rt], 0, 0, 0);
        }
        __syncthreads();   // all BUF reads complete
        u16* scr = BUF + 16384 + wave * 640;   // chunks 32+ (dead region)
#pragma unroll
        for (int s = 0; s < 2; s++) {
            const int nt = wave * 2 + s;
#pragma unroll
            for (int h = 0; h < 2; h++) {
#pragma unroll
                for (int r2 = 0; r2 < 2; r2++) {
                    f32x4 v = acc[s][2 * h + r2];
                    short4v p;
#pragma unroll
                    for (int rr = 0; rr < 4; rr++) p[rr] = (short)f2bf_fast(v[rr]);
                    *(short4v*)(scr + nl * 40 + r2 * 16 + quad * 4) = p;
                }
                short8 hwf = *(const short8*)(scr + nl * 40 + quad * 8);
                *(short8*)(BUF + (nt * 2 + h) * 512 + lane * 8) = hwf;
            }
        }
        __syncthreads();
    };

    layerT(std::integral_constant<int, 8>{},  ws + WS_W1, ws + WS_B1);
    layerT(std::integral_constant<int, 16>{}, ws + WS_W2, ws + WS_B2);
    layer3(ws + WS_W3);

    // final: out = relu(A_norm @ hw3 + b3); 8 waves cover the element
    // (8 n-tiles/wave); f32 staged in-place over BUF, coalesced store.
    {
        const int rt2 = wave & 3, nt0 = (wave >> 2) * 8;
        short8 aA[2];
#pragma unroll
        for (int h = 0; h < 2; h++)
            aA[h] = *(const short8*)(ws + WS_ADJA + (h * 4 + quad) * 512 + (rt2 * 16 + nl) * 8);
        f32x4 accv[8];
#pragma unroll
        for (int ni = 0; ni < 8; ni++) {
            const int nt = nt0 + ni;
            short8 b0v = *(const short8*)(BUF + (nt * 2 + 0) * 512 + lane * 8);
            short8 b1v = *(const short8*)(BUF + (nt * 2 + 1) * 512 + lane * 8);
            f32x4 a = f32x4{0.f, 0.f, 0.f, 0.f};
            a = __builtin_amdgcn_mfma_f32_16x16x32_bf16(aA[0], b0v, a, 0, 0, 0);
            a = __builtin_amdgcn_mfma_f32_16x16x32_bf16(aA[1], b1v, a, 0, 0, 0);
            accv[ni] = a;
        }
        __syncthreads();   // all BUF reads complete -> f32 overwrite legal
        {
            float* Hf = (float*)BUF;
#pragma unroll
            for (int ni = 0; ni < 8; ni++) {
                const int n = (nt0 + ni) * 16 + nl;
                const float bv = bf2f(ws[WS_B3 + n]);
#pragma unroll
                for (int rr = 0; rr < 4; rr++) {
                    const int m2 = rt2 * 16 + quad * 4 + rr;
                    Hf[m2 * 256 + n] = fmaxf(accv[ni][rr] + bv, 0.f);
                }
            }
        }
        __syncthreads();
        if (isf32) {
            float4* outv = (float4*)((float*)out + (size_t)bb * 16384);
            const float4* Hv = (const float4*)BUF;
#pragma unroll
            for (int p4 = 0; p4 < 8; p4++) outv[p4 * 512 + t] = Hv[p4 * 512 + t];
        } else {
            u16* outu = (u16*)out + (size_t)bb * 16384;
            const float* Hf = (const float*)BUF;
#pragma unroll
            for (int p4 = 0; p4 < 8; p4++) {
                const int idx = (p4 * 512 + t) * 4;
                float4 v = *(const float4*)(Hf + idx);
                short4v pk;
                pk[0] = (short)f2bf_fast(v.x); pk[1] = (short)f2bf_fast(v.y);
                pk[2] = (short)f2bf_fast(v.z); pk[3] = (short)f2bf_fast(v.w);
                *(short4v*)(outu + idx) = pk;
            }
        }
    }
}

// ---------------------------------------------------------------------------
extern "C" void kernel_launch(void* const* d_in, const int* in_sizes, int n_in,
                              void* d_out, int out_size, void* d_ws, size_t ws_size,
                              hipStream_t stream) {
    const int* allocs = (const int*)d_in[0];
    const void* qembs = d_in[1];
    const void* dummy = d_in[2];
    const int* eidx   = (const int*)d_in[3];
    const void* ew    = d_in[4];
    const void* W1 = d_in[5];
    const void* b1 = d_in[6];
    const void* W2 = d_in[7];
    const void* b2 = d_in[8];
    const void* W3 = d_in[9];
    const void* b3 = d_in[10];
    u16* ws = (u16*)d_ws;

    prep<<<512, 512, 0, stream>>>(eidx, ew, qembs, dummy, W1, b1, W2, b2, W3, b3, ws);
    fused<<<512, 512, 0, stream>>>(allocs, ws, d_out);
}